// Round 1
// baseline (4498.639 us; speedup 1.0000x reference)
//
#include <hip/hip_runtime.h>
#include <math.h>

#define IMH 256
#define IMW 256
#define NBT 8
#define NF  64
#define HW  65536

// power-iteration batching
#define TSZ 16
#define MB 10          // iterations per batch
#define NBATCH 30      // 30*10 = 300 total
#define HALO (2*MB)    // 20 (operator radius 2 per step)
#define RG (TSZ + 2*HALO)   // 56
#define RG2 (RG*RG)         // 3136

// ws float offsets (small table area only; ws needs just ~1.7 KB)
#define WS_SM   0      // 81: masked-operator table Sm[dr][dq]
#define WS_K5   81     // 25: fused interior 5x5 kernel
#define WS_ACC  106    // 301: per-level squared norms
#define WS_LIP2 407
#define WS_TAU  408
#define WS_SIGMA 409

// -------------------------------------------------------------------------
// Setup: build S/K5 tables from w, zero norm accumulators.
// Sm[a][b] with a=(dry+1)*3+(drx+1), b=(dqy+1)*3+(dqx+1):
//   Sm = sum_f w_f[1-dry][1-drx] * w_f[dqy+1][dqx+1]
// z[p] = sum_{dr: p+dr in img} sum_{dq} Sm[dr][dq] * x[p+dr+dq]  (x zero-padded)
// Interior (p at least 1 from edge): z[p] = sum_{|d|<=2} K5[d] x[p+d],
//   K5[d] = sum_{dr+dq=d} Sm[dr][dq].
// -------------------------------------------------------------------------
__global__ void setup_kernel(const float* __restrict__ w, float* __restrict__ ws) {
    int t = threadIdx.x;
    for (int i = t; i < 301; i += blockDim.x) ws[WS_ACC + i] = 0.f;
    __shared__ float smS[81];
    if (t < 81) {
        int a = t / 9, bq = t % 9;
        int dry = a / 3 - 1, drx = a % 3 - 1;
        int dqy = bq / 3 - 1, dqx = bq % 3 - 1;
        int r_idx = (1 - dry) * 3 + (1 - drx);
        int q_idx = (dqy + 1) * 3 + (dqx + 1);
        float s = 0.f;
        for (int f = 0; f < NF; ++f) s += w[f * 9 + r_idx] * w[f * 9 + q_idx];
        smS[t] = s;
        ws[WS_SM + t] = s;
    }
    __syncthreads();
    if (t < 25) {
        int dy = t / 5 - 2, dx = t % 5 - 2;
        float k = 0.f;
        for (int a = 0; a < 9; ++a) {
            int dry = a / 3 - 1, drx = a % 3 - 1;
            for (int bq = 0; bq < 9; ++bq) {
                int dqy = bq / 3 - 1, dqx = bq % 3 - 1;
                if (dry + dqy == dy && drx + dqx == dx) k += smS[a * 9 + bq];
            }
        }
        ws[WS_K5 + t] = k;
    }
}

// -------------------------------------------------------------------------
// One batch of MB power-iteration steps. 256 blocks = 16x16 tiles of 16^2.
// Loads (TSZ+2*HALO)^2 region into LDS, runs MB radius-2 steps locally,
// records per-level ||.||^2 of the central tile, writes central tile out.
// gin/gout ping-pong buffers live in d_out's output1 region (scratch).
// -------------------------------------------------------------------------
__global__ __launch_bounds__(256) void pi_batch_kernel(
    float* __restrict__ ws, float* __restrict__ gbuf, int batch) {
    __shared__ float bufA[RG2];
    __shared__ float bufB[RG2];
    const int tid = threadIdx.x;
    const int bid = blockIdx.x;
    const int ox = (bid % 16) * TSZ - HALO;
    const int oy = (bid / 16) * TSZ - HALO;
    const float* gin = gbuf + ((batch & 1) ? HW : 0);
    float* gout      = gbuf + ((batch & 1) ? 0 : HW);

    float k5[25];
#pragma unroll
    for (int i = 0; i < 25; ++i) k5[i] = ws[WS_K5 + i];
    const float* sm = ws + WS_SM;

    const float inv_n = (batch == 0) ? (1.0f / 256.0f)
                                     : (1.0f / sqrtf(ws[WS_ACC + batch * MB]));

    // load region (zeros outside image)
    for (int i = tid; i < RG2; i += 256) {
        int ly = i / RG, lx = i % RG;
        int gy = oy + ly, gx = ox + lx;
        float v = 0.f;
        if ((unsigned)gy < IMH && (unsigned)gx < IMW)
            v = (batch == 0) ? inv_n : gin[gy * IMW + gx] * inv_n;
        bufA[i] = v;
    }
    __syncthreads();

    float* cur = bufA;
    float* nxt = bufB;
#pragma unroll
    for (int s = 0; s < MB; ++s) {
        const int side = RG - 4 * (s + 1);
        const int off = 2 * (s + 1);
        float part = 0.f;
        for (int i = tid; i < side * side; i += 256) {
            int ly = off + i / side, lx = off + i % side;
            int gy = oy + ly, gx = ox + lx;
            float z = 0.f;
            if ((unsigned)gy < IMH && (unsigned)gx < IMW) {
                const float* xp = cur + ly * RG + lx;
                if (gy >= 1 && gy <= IMH - 2 && gx >= 1 && gx <= IMW - 2) {
                    // interior: fused 5x5
#pragma unroll
                    for (int dy = -2; dy <= 2; ++dy)
#pragma unroll
                        for (int dx = -2; dx <= 2; ++dx)
                            z += k5[(dy + 2) * 5 + (dx + 2)] * xp[dy * RG + dx];
                } else {
                    // boundary: masked two-level form
#pragma unroll
                    for (int a = 0; a < 9; ++a) {
                        int dry = a / 3 - 1, drx = a % 3 - 1;
                        if ((unsigned)(gy + dry) < IMH && (unsigned)(gx + drx) < IMW) {
                            float ss = 0.f;
#pragma unroll
                            for (int bq = 0; bq < 9; ++bq) {
                                int dqy = bq / 3 - 1, dqx = bq % 3 - 1;
                                ss += sm[a * 9 + bq] *
                                      xp[(dry + dqy) * RG + (drx + dqx)];
                            }
                            z += ss;
                        }
                    }
                }
            }
            nxt[ly * RG + lx] = z;
            if (ly >= HALO && ly < HALO + TSZ && lx >= HALO && lx < HALO + TSZ)
                part += z * z;
        }
        // per-wave reduce, lane0 of each wave atomically accumulates
#pragma unroll
        for (int o = 32; o > 0; o >>= 1) part += __shfl_down(part, o, 64);
        if ((tid & 63) == 0) atomicAdd(&ws[WS_ACC + batch * MB + s + 1], part);
        __syncthreads();
        float* tmp = cur; cur = nxt; nxt = tmp;
    }

    // write central tile (exactly 256 px, one per thread)
    {
        int ly = HALO + tid / TSZ, lx = HALO + tid % TSZ;
        int gy = oy + ly, gx = ox + lx;
        gout[gy * IMW + gx] = cur[ly * RG + lx];
    }
}

// -------------------------------------------------------------------------
// Replay the exact while-loop stopping rule on the recorded norm sequence.
// val_k = n_k / n_{k-1} per batch (input renormalized each batch -> n_0=1).
// -------------------------------------------------------------------------
__global__ void finalize_kernel(float* __restrict__ ws,
                                const float* __restrict__ beta,
                                const float* __restrict__ log_sigma) {
    if (threadIdx.x != 0 || blockIdx.x != 0) return;
    float val = 1.0f;
    int k = 0;
    bool stopped = false;
    for (int b = 0; b < NBATCH && !stopped; ++b) {
        float nprev = 1.0f;
        for (int s = 1; s <= MB; ++s) {
            float n = sqrtf(ws[WS_ACC + b * MB + s]);
            float v = n / nprev;
            nprev = n;
            float rel = fabsf(v - val) / val;
            val = v;
            ++k;
            if (rel < 1e-4f || k >= 300) { stopped = true; break; }
        }
    }
    float lip2 = val;
    float sigma = expf(log_sigma[0]) + 0.05f;
    float tau = 0.99f / (beta[0] * 0.5f + sigma * lip2);
    ws[WS_LIP2] = lip2;
    ws[WS_TAU] = tau;
    ws[WS_SIGMA] = sigma;
}

// -------------------------------------------------------------------------
// output0: Dx = x - tau*(HtH.*x) - tau*conv_t(u) + tau*bias; clip [0,1]
// block = one image row (256 x), grid = (y, b). conv_t fused over 64 ch.
// -------------------------------------------------------------------------
__global__ __launch_bounds__(256) void out0_kernel(
    const float* __restrict__ x_in, const float* __restrict__ u_in,
    const float* __restrict__ bias, const float* __restrict__ HtH,
    const float* __restrict__ w, const float* __restrict__ ws,
    float* __restrict__ out0) {
    const int x = threadIdx.x;
    const int y = blockIdx.x;
    const int b = blockIdx.y;
    const float tau = ws[WS_TAU];
    const int p = y * IMW + x;
    float ct = 0.f;
    const float* ub = u_in + (size_t)b * NF * HW;
#pragma unroll 1
    for (int f = 0; f < NF; ++f) {
        const float* uf = ub + f * HW;
        const float* wf = w + f * 9;
#pragma unroll
        for (int dy = -1; dy <= 1; ++dy) {
            int yy = y + dy;
            if ((unsigned)yy >= IMH) continue;
#pragma unroll
            for (int dx = -1; dx <= 1; ++dx) {
                int xx = x + dx;
                if ((unsigned)xx >= IMW) continue;
                ct += wf[(1 - dy) * 3 + (1 - dx)] * uf[yy * IMW + xx];
            }
        }
    }
    float xi = x_in[b * HW + p];
    float Dx = xi - tau * (HtH[p] * xi) - tau * ct + tau * bias[b * HW + p];
    out0[b * HW + p] = fminf(fmaxf(Dx, 0.f), 1.f);
}

// -------------------------------------------------------------------------
// output1: Du = 2*sigma*conv(out0)_f - sigma*conv(x_in)_f + u; clip [-lam,lam]
// block = one row, grid = (y, f, b).
// -------------------------------------------------------------------------
__global__ __launch_bounds__(256) void out1_kernel(
    const float* __restrict__ x_in, const float* __restrict__ u_in,
    const float* __restrict__ lambd, const float* __restrict__ w,
    const float* __restrict__ ws, const float* __restrict__ out0,
    float* __restrict__ out1) {
    const int x = threadIdx.x;
    const int y = blockIdx.x;
    const int f = blockIdx.y;
    const int b = blockIdx.z;
    const float sigma = ws[WS_SIGMA];
    const float lam = lambd[0];
    const float* wf = w + f * 9;
    const float* o0 = out0 + b * HW;
    const float* xb = x_in + b * HW;
    float s1 = 0.f, s2 = 0.f;
#pragma unroll
    for (int dy = -1; dy <= 1; ++dy) {
        int yy = y + dy;
        if ((unsigned)yy >= IMH) continue;
#pragma unroll
        for (int dx = -1; dx <= 1; ++dx) {
            int xx = x + dx;
            if ((unsigned)xx >= IMW) continue;
            float wv = wf[(dy + 1) * 3 + (dx + 1)];
            s1 += wv * o0[yy * IMW + xx];
            s2 += wv * xb[yy * IMW + xx];
        }
    }
    size_t idx = (size_t)(b * NF + f) * HW + y * IMW + x;
    float Du = 2.0f * sigma * s1 - sigma * s2 + u_in[idx];
    out1[idx] = fminf(fmaxf(Du, -lam), lam);
}

extern "C" void kernel_launch(void* const* d_in, const int* in_sizes, int n_in,
                              void* d_out, int out_size, void* d_ws, size_t ws_size,
                              hipStream_t stream) {
    const float* x_in = (const float*)d_in[0];
    const float* u_in = (const float*)d_in[1];
    const float* bias = (const float*)d_in[2];
    const float* beta = (const float*)d_in[3];
    const float* lambd = (const float*)d_in[4];
    const float* HtH = (const float*)d_in[5];
    const float* w = (const float*)d_in[6];
    const float* log_sigma = (const float*)d_in[7];
    float* ws = (float*)d_ws;
    float* out0 = (float*)d_out;
    float* out1 = out0 + (size_t)NBT * HW;
    // ping-pong power-iteration image buffers live at the start of the
    // output1 region (written long before out1_kernel overwrites it).
    float* gbuf = out1;

    setup_kernel<<<1, 128, 0, stream>>>(w, ws);
    for (int b = 0; b < NBATCH; ++b)
        pi_batch_kernel<<<256, 256, 0, stream>>>(ws, gbuf, b);
    finalize_kernel<<<1, 64, 0, stream>>>(ws, beta, log_sigma);
    out0_kernel<<<dim3(IMH, NBT), 256, 0, stream>>>(x_in, u_in, bias, HtH, w, ws, out0);
    out1_kernel<<<dim3(IMH, NF, NBT), 256, 0, stream>>>(x_in, u_in, lambd, w, ws, out0, out1);
}

// Round 2
// 3112.403 us; speedup vs baseline: 1.4454x; 1.4454x over previous
//
#include <hip/hip_runtime.h>
#include <math.h>

#define IMH 256
#define IMW 256
#define NBT 8
#define NF  64
#define HW  65536

// power-iteration batching
#define TSZ 16
#define MB 10          // iterations per batch
#define NBATCH 30      // 30*10 = 300 total
#define HALO (2*MB)    // 20 (operator radius 2 per step)
#define RG (TSZ + 2*HALO)   // 56
#define RG2 (RG*RG)         // 3136

// ws float offsets (small table area only)
#define WS_SM   0      // 81: masked-operator table Sm[dr][dq]
#define WS_K5   81     // 25: fused interior 5x5 kernel
#define WS_ACC  106    // 301: per-level squared norms (slot 1..300 used)
#define WS_LIP2 407
#define WS_TAU  408
#define WS_SIGMA 409

// -------------------------------------------------------------------------
// Setup: build S/K5 tables from w.
// -------------------------------------------------------------------------
__global__ void setup_kernel(const float* __restrict__ w, float* __restrict__ ws) {
    int t = threadIdx.x;
    __shared__ float smS[81];
    if (t < 81) {
        int a = t / 9, bq = t % 9;
        int dry = a / 3 - 1, drx = a % 3 - 1;
        int dqy = bq / 3 - 1, dqx = bq % 3 - 1;
        int r_idx = (1 - dry) * 3 + (1 - drx);
        int q_idx = (dqy + 1) * 3 + (dqx + 1);
        float s = 0.f;
        for (int f = 0; f < NF; ++f) s += w[f * 9 + r_idx] * w[f * 9 + q_idx];
        smS[t] = s;
        ws[WS_SM + t] = s;
    }
    __syncthreads();
    if (t < 25) {
        int dy = t / 5 - 2, dx = t % 5 - 2;
        float k = 0.f;
        for (int a = 0; a < 9; ++a) {
            int dry = a / 3 - 1, drx = a % 3 - 1;
            for (int bq = 0; bq < 9; ++bq) {
                int dqy = bq / 3 - 1, dqx = bq % 3 - 1;
                if (dry + dqy == dy && drx + dqx == dx) k += smS[a * 9 + bq];
            }
        }
        ws[WS_K5 + t] = k;
    }
}

// -------------------------------------------------------------------------
// One batch of MB power-iteration steps. 256 blocks = 16x16 tiles of 16^2.
// NO atomics: each wave stores its ||.||^2 partial to a private slot in
// part[level*1024 + block*4 + wave]. inv_n for batch>0 is re-reduced from
// the previous batch's last level (4 KB, L2-resident).
// -------------------------------------------------------------------------
__global__ __launch_bounds__(256) void pi_batch_kernel(
    const float* __restrict__ ws, float* __restrict__ gbuf,
    float* __restrict__ part, int batch) {
    __shared__ float bufA[RG2];
    __shared__ float bufB[RG2];
    __shared__ float sred[4];
    const int tid = threadIdx.x;
    const int bid = blockIdx.x;
    const int wid = tid >> 6;
    const int lane = tid & 63;
    const int ox = (bid % 16) * TSZ - HALO;
    const int oy = (bid / 16) * TSZ - HALO;
    const float* gin = gbuf + ((batch & 1) ? HW : 0);
    float* gout      = gbuf + ((batch & 1) ? 0 : HW);

    float k5[25];
#pragma unroll
    for (int i = 0; i < 25; ++i) k5[i] = ws[WS_K5 + i];
    const float* sm = ws + WS_SM;

    float inv_n;
    if (batch == 0) {
        inv_n = 1.0f / 256.0f;
    } else {
        const float* pp = part + (size_t)(batch * MB - 1) * 1024;
        float s = pp[tid] + pp[tid + 256] + pp[tid + 512] + pp[tid + 768];
#pragma unroll
        for (int o = 32; o > 0; o >>= 1) s += __shfl_down(s, o, 64);
        if (lane == 0) sred[wid] = s;
        __syncthreads();
        inv_n = 1.0f / sqrtf(sred[0] + sred[1] + sred[2] + sred[3]);
        __syncthreads();
    }

    // load region (zeros outside image)
    for (int i = tid; i < RG2; i += 256) {
        int ly = i / RG, lx = i % RG;
        int gy = oy + ly, gx = ox + lx;
        float v = 0.f;
        if ((unsigned)gy < IMH && (unsigned)gx < IMW)
            v = (batch == 0) ? inv_n : gin[gy * IMW + gx] * inv_n;
        bufA[i] = v;
    }
    __syncthreads();

    float* cur = bufA;
    float* nxt = bufB;
#pragma unroll 1
    for (int s = 0; s < MB; ++s) {
        const int side = RG - 4 * (s + 1);
        const int off = 2 * (s + 1);
        float partv = 0.f;
        // div-free mapping: lane = x within row (idle if >= side),
        // wid + 4*k = row index.
        const int lx = off + lane;
        const int gx = ox + lx;
        if (lane < side) {
            for (int ry = wid; ry < side; ry += 4) {
                const int ly = off + ry;
                const int gy = oy + ly;
                float z = 0.f;
                if ((unsigned)gy < IMH && (unsigned)gx < IMW) {
                    const float* xp = cur + ly * RG + lx;
                    if (gy >= 1 && gy <= IMH - 2 && gx >= 1 && gx <= IMW - 2) {
                        // interior: fused 5x5, row sums to break FMA chain
                        float acc[5];
#pragma unroll
                        for (int dy = -2; dy <= 2; ++dy) {
                            const float* row = xp + dy * RG;
                            const float* kk = k5 + (dy + 2) * 5;
                            float a = kk[0] * row[-2];
                            a += kk[1] * row[-1];
                            a += kk[2] * row[0];
                            a += kk[3] * row[1];
                            a += kk[4] * row[2];
                            acc[dy + 2] = a;
                        }
                        z = ((acc[0] + acc[1]) + (acc[2] + acc[3])) + acc[4];
                    } else {
                        // boundary: masked two-level form
#pragma unroll
                        for (int a = 0; a < 9; ++a) {
                            int dry = a / 3 - 1, drx = a % 3 - 1;
                            if ((unsigned)(gy + dry) < IMH && (unsigned)(gx + drx) < IMW) {
                                float ss = 0.f;
#pragma unroll
                                for (int bq = 0; bq < 9; ++bq) {
                                    int dqy = bq / 3 - 1, dqx = bq % 3 - 1;
                                    ss += sm[a * 9 + bq] *
                                          xp[(dry + dqy) * RG + (drx + dqx)];
                                }
                                z += ss;
                            }
                        }
                    }
                }
                nxt[ly * RG + lx] = z;
                if (ly >= HALO && ly < HALO + TSZ && lx >= HALO && lx < HALO + TSZ)
                    partv += z * z;
            }
        }
        // per-wave reduce; wave leader stores to its private slot (no atomic)
#pragma unroll
        for (int o = 32; o > 0; o >>= 1) partv += __shfl_down(partv, o, 64);
        if (lane == 0)
            part[(size_t)(batch * MB + s) * 1024 + (bid << 2) + wid] = partv;
        __syncthreads();
        float* tmp = cur; cur = nxt; nxt = tmp;
    }

    // write central tile (exactly 256 px, one per thread)
    {
        int ly = HALO + (tid >> 4), lx = HALO + (tid & 15);
        int gy = oy + ly, gx = ox + lx;
        gout[gy * IMW + gx] = cur[ly * RG + lx];
    }
}

// -------------------------------------------------------------------------
// Sum the 1024 per-wave partials of each level into ws norm slots.
// -------------------------------------------------------------------------
__global__ __launch_bounds__(256) void reduce_kernel(
    const float* __restrict__ part, float* __restrict__ ws) {
    const int lev = blockIdx.x;       // 0..299
    const int t = threadIdx.x;
    __shared__ float sr[4];
    const float* pp = part + (size_t)lev * 1024;
    float s = pp[t] + pp[t + 256] + pp[t + 512] + pp[t + 768];
#pragma unroll
    for (int o = 32; o > 0; o >>= 1) s += __shfl_down(s, o, 64);
    if ((t & 63) == 0) sr[t >> 6] = s;
    __syncthreads();
    if (t == 0) ws[WS_ACC + 1 + lev] = sr[0] + sr[1] + sr[2] + sr[3];
}

// -------------------------------------------------------------------------
// Replay the exact while-loop stopping rule on the recorded norm sequence.
// -------------------------------------------------------------------------
__global__ void finalize_kernel(float* __restrict__ ws,
                                const float* __restrict__ beta,
                                const float* __restrict__ log_sigma) {
    if (threadIdx.x != 0 || blockIdx.x != 0) return;
    float val = 1.0f;
    int k = 0;
    bool stopped = false;
    for (int b = 0; b < NBATCH && !stopped; ++b) {
        float nprev = 1.0f;
        for (int s = 1; s <= MB; ++s) {
            float n = sqrtf(ws[WS_ACC + b * MB + s]);
            float v = n / nprev;
            nprev = n;
            float rel = fabsf(v - val) / val;
            val = v;
            ++k;
            if (rel < 1e-4f || k >= 300) { stopped = true; break; }
        }
    }
    float lip2 = val;
    float sigma = expf(log_sigma[0]) + 0.05f;
    float tau = 0.99f / (beta[0] * 0.5f + sigma * lip2);
    ws[WS_LIP2] = lip2;
    ws[WS_TAU] = tau;
    ws[WS_SIGMA] = sigma;
}

// -------------------------------------------------------------------------
// output0: Dx = x - tau*(HtH.*x) - tau*conv_t(u) + tau*bias; clip [0,1]
// wave = one image row; lane = 4-px quad (float4); x-halo via shuffles.
// grid = (IMH/4, NBT), block = 256 (4 waves = 4 rows).
// -------------------------------------------------------------------------
__global__ __launch_bounds__(256) void out0_kernel(
    const float* __restrict__ x_in, const float* __restrict__ u_in,
    const float* __restrict__ bias, const float* __restrict__ HtH,
    const float* __restrict__ w, const float* __restrict__ ws,
    float* __restrict__ out0) {
    const int tid = threadIdx.x;
    const int lane = tid & 63;
    const int wid = tid >> 6;
    const int y = blockIdx.x * 4 + wid;
    const int b = blockIdx.y;
    const int x0 = lane * 4;
    const float tau = ws[WS_TAU];
    float4 ct = {0.f, 0.f, 0.f, 0.f};
    const float* ub = u_in + (size_t)b * NF * HW;
#pragma unroll 2
    for (int f = 0; f < NF; ++f) {
        const float* uf = ub + (size_t)f * HW;
        const float* wf = w + f * 9;
#pragma unroll
        for (int dy = -1; dy <= 1; ++dy) {
            int yy = y + dy;
            float4 v = {0.f, 0.f, 0.f, 0.f};
            if ((unsigned)yy < IMH)
                v = *(const float4*)(uf + yy * IMW + x0);
            float m1 = __shfl_up(v.w, 1);
            if (lane == 0) m1 = 0.f;
            float p4 = __shfl_down(v.x, 1);
            if (lane == 63) p4 = 0.f;
            // conv_t weight row: w[(1-dy)*3 + (1-dx)]
            const float w2 = wf[(1 - dy) * 3 + 2];   // dx=-1
            const float w1 = wf[(1 - dy) * 3 + 1];   // dx= 0
            const float w0 = wf[(1 - dy) * 3 + 0];   // dx=+1
            ct.x += w2 * m1  + w1 * v.x + w0 * v.y;
            ct.y += w2 * v.x + w1 * v.y + w0 * v.z;
            ct.z += w2 * v.y + w1 * v.z + w0 * v.w;
            ct.w += w2 * v.z + w1 * v.w + w0 * p4;
        }
    }
    const int p = y * IMW + x0;
    const float4 xi = *(const float4*)(x_in + (size_t)b * HW + p);
    const float4 hh = *(const float4*)(HtH + p);
    const float4 bs = *(const float4*)(bias + (size_t)b * HW + p);
    float4 o;
    o.x = fminf(fmaxf(xi.x - tau * (hh.x * xi.x) - tau * ct.x + tau * bs.x, 0.f), 1.f);
    o.y = fminf(fmaxf(xi.y - tau * (hh.y * xi.y) - tau * ct.y + tau * bs.y, 0.f), 1.f);
    o.z = fminf(fmaxf(xi.z - tau * (hh.z * xi.z) - tau * ct.z + tau * bs.z, 0.f), 1.f);
    o.w = fminf(fmaxf(xi.w - tau * (hh.w * xi.w) - tau * ct.w + tau * bs.w, 0.f), 1.f);
    *(float4*)(out0 + (size_t)b * HW + p) = o;
}

// -------------------------------------------------------------------------
// output1: Du = 2*sigma*conv(out0)_f - sigma*conv(x_in)_f + u; clip [-lam,lam]
// wave = one row of one (f,b); lane = 4-px quad. grid = (IMH/4, NF, NBT).
// -------------------------------------------------------------------------
__global__ __launch_bounds__(256) void out1_kernel(
    const float* __restrict__ x_in, const float* __restrict__ u_in,
    const float* __restrict__ lambd, const float* __restrict__ w,
    const float* __restrict__ ws, const float* __restrict__ out0,
    float* __restrict__ out1) {
    const int tid = threadIdx.x;
    const int lane = tid & 63;
    const int wid = tid >> 6;
    const int y = blockIdx.x * 4 + wid;
    const int f = blockIdx.y;
    const int b = blockIdx.z;
    const int x0 = lane * 4;
    const float sigma = ws[WS_SIGMA];
    const float lam = lambd[0];
    const float* wf = w + f * 9;
    float wr[9];
#pragma unroll
    for (int i = 0; i < 9; ++i) wr[i] = wf[i];
    const float* o0 = out0 + (size_t)b * HW;
    const float* xb = x_in + (size_t)b * HW;
    float4 s1 = {0.f, 0.f, 0.f, 0.f};
    float4 s2 = {0.f, 0.f, 0.f, 0.f};
#pragma unroll
    for (int dy = -1; dy <= 1; ++dy) {
        int yy = y + dy;
        float4 a = {0.f, 0.f, 0.f, 0.f};
        float4 c = {0.f, 0.f, 0.f, 0.f};
        if ((unsigned)yy < IMH) {
            a = *(const float4*)(o0 + yy * IMW + x0);
            c = *(const float4*)(xb + yy * IMW + x0);
        }
        float am1 = __shfl_up(a.w, 1);  if (lane == 0) am1 = 0.f;
        float ap4 = __shfl_down(a.x, 1); if (lane == 63) ap4 = 0.f;
        float cm1 = __shfl_up(c.w, 1);  if (lane == 0) cm1 = 0.f;
        float cp4 = __shfl_down(c.x, 1); if (lane == 63) cp4 = 0.f;
        // conv weight row: w[(dy+1)*3 + (dx+1)]
        const float w0 = wr[(dy + 1) * 3 + 0];   // dx=-1
        const float w1 = wr[(dy + 1) * 3 + 1];   // dx= 0
        const float w2 = wr[(dy + 1) * 3 + 2];   // dx=+1
        s1.x += w0 * am1 + w1 * a.x + w2 * a.y;
        s1.y += w0 * a.x + w1 * a.y + w2 * a.z;
        s1.z += w0 * a.y + w1 * a.z + w2 * a.w;
        s1.w += w0 * a.z + w1 * a.w + w2 * ap4;
        s2.x += w0 * cm1 + w1 * c.x + w2 * c.y;
        s2.y += w0 * c.x + w1 * c.y + w2 * c.z;
        s2.z += w0 * c.y + w1 * c.z + w2 * c.w;
        s2.w += w0 * c.z + w1 * c.w + w2 * cp4;
    }
    const size_t idx = (size_t)(b * NF + f) * HW + y * IMW + x0;
    const float4 uq = *(const float4*)(u_in + idx);
    float4 o;
    o.x = fminf(fmaxf(2.f * sigma * s1.x - sigma * s2.x + uq.x, -lam), lam);
    o.y = fminf(fmaxf(2.f * sigma * s1.y - sigma * s2.y + uq.y, -lam), lam);
    o.z = fminf(fmaxf(2.f * sigma * s1.z - sigma * s2.z + uq.z, -lam), lam);
    o.w = fminf(fmaxf(2.f * sigma * s1.w - sigma * s2.w + uq.w, -lam), lam);
    *(float4*)(out1 + idx) = o;
}

extern "C" void kernel_launch(void* const* d_in, const int* in_sizes, int n_in,
                              void* d_out, int out_size, void* d_ws, size_t ws_size,
                              hipStream_t stream) {
    const float* x_in = (const float*)d_in[0];
    const float* u_in = (const float*)d_in[1];
    const float* bias = (const float*)d_in[2];
    const float* beta = (const float*)d_in[3];
    const float* lambd = (const float*)d_in[4];
    const float* HtH = (const float*)d_in[5];
    const float* w = (const float*)d_in[6];
    const float* log_sigma = (const float*)d_in[7];
    float* ws = (float*)d_ws;
    float* out0 = (float*)d_out;
    float* out1 = out0 + (size_t)NBT * HW;
    // scratch lives in the (not yet written) output1 region:
    //   gbuf: 2*HW floats ping-pong image; part: 300*1024 per-wave partials
    float* gbuf = out1;
    float* part = out1 + 2 * HW;

    setup_kernel<<<1, 128, 0, stream>>>(w, ws);
    for (int b = 0; b < NBATCH; ++b)
        pi_batch_kernel<<<256, 256, 0, stream>>>(ws, gbuf, part, b);
    reduce_kernel<<<300, 256, 0, stream>>>(part, ws);
    finalize_kernel<<<1, 64, 0, stream>>>(ws, beta, log_sigma);
    out0_kernel<<<dim3(IMH / 4, NBT), 256, 0, stream>>>(x_in, u_in, bias, HtH, w, ws, out0);
    out1_kernel<<<dim3(IMH / 4, NF, NBT), 256, 0, stream>>>(x_in, u_in, lambd, w, ws, out0, out1);
}

// Round 3
// 1111.803 us; speedup vs baseline: 4.0463x; 2.7994x over previous
//
#include <hip/hip_runtime.h>
#include <math.h>

#define IMH 256
#define IMW 256
#define NBT 8
#define NF  64
#define HW  65536

// power-iteration batching
#define TSZ 16
#define MB 10          // iterations per batch
#define NBATCH 30      // 30*10 = 300 total
#define HALO (2*MB)    // 20 (operator radius 2 per step)
// LDS buffer: 60 rows x 64 cols (+4 float pad front, +4 tail) per buffer.
// region (56x56) lives at rows [2,58), cols [4,60); central 16x16 tile at
// rows [22,38), cols [24,40) (quad-aligned).
#define BROW 64
#define BUFSZ (60*64 + 8)

// ws float offsets
#define WS_SM   0      // 81: masked-operator table Sm[dr][dq]
#define WS_K5   81     // 25: fused interior 5x5 kernel
#define WS_ET   106    // 5: top-edge correction kernel (applied at gy==0)
#define WS_EB   111    // 5: bottom-edge (gy==IMH-1)
#define WS_EL   116    // 5: left-edge (gx==0, vertical)
#define WS_ER   121    // 5: right-edge (gx==IMW-1, vertical)
#define WS_C4   126    // 4: corner add-backs TL,TR,BL,BR
#define WS_ACC  130    // 301: per-level squared norms (slot 1..300 used)
#define WS_LIP2 431
#define WS_TAU  432
#define WS_SIGMA 433

// -------------------------------------------------------------------------
// Setup: build Sm, K5, and edge-correction tables from w.
// Sm[a][b], a=(dry+1)*3+(drx+1), b=(dqy+1)*3+(dqx+1):
//   Sm = sum_f w_f[1-dry][1-drx] * w_f[dqy+1][dqx+1]
// z[p] = sum_{dr: p+dr in img} sum_{dq} Sm[dr][dq] x[p+dr+dq]  (x==0 outside)
// Interior: 5x5 K5. Image-edge ring: K5 minus edge kernels (with x==0
// outside, the dr-outside corrections collapse to dy==0 (y-edges) and
// dx==0 (x-edges) + single-coefficient corner add-backs).
// -------------------------------------------------------------------------
__global__ void setup_kernel(const float* __restrict__ w, float* __restrict__ ws) {
    int t = threadIdx.x;
    __shared__ float smS[81];
    if (t < 81) {
        int a = t / 9, bq = t % 9;
        int dry = a / 3 - 1, drx = a % 3 - 1;
        int dqy = bq / 3 - 1, dqx = bq % 3 - 1;
        int r_idx = (1 - dry) * 3 + (1 - drx);
        int q_idx = (dqy + 1) * 3 + (dqx + 1);
        float s = 0.f;
        for (int f = 0; f < NF; ++f) s += w[f * 9 + r_idx] * w[f * 9 + q_idx];
        smS[t] = s;
        ws[WS_SM + t] = s;
    }
    __syncthreads();
    if (t < 25) {
        int dy = t / 5 - 2, dx = t % 5 - 2;
        float k = 0.f;
        for (int a = 0; a < 9; ++a) {
            int dry = a / 3 - 1, drx = a % 3 - 1;
            for (int bq = 0; bq < 9; ++bq) {
                int dqy = bq / 3 - 1, dqx = bq % 3 - 1;
                if (dry + dqy == dy && drx + dqx == dx) k += smS[a * 9 + bq];
            }
        }
        ws[WS_K5 + t] = k;
    }
    if (t == 0) {
        for (int dd = 0; dd < 5; ++dd) {
            int dx = dd - 2;
            float et = 0.f, eb = 0.f, el = 0.f, er = 0.f;
            for (int dr = -1; dr <= 1; ++dr) {
                int dq = dx - dr;
                if (dq < -1 || dq > 1) continue;
                et += smS[(0 * 3 + dr + 1) * 9 + (2 * 3 + dq + 1)];   // dry=-1,dqy=+1
                eb += smS[(2 * 3 + dr + 1) * 9 + (0 * 3 + dq + 1)];   // dry=+1,dqy=-1
                el += smS[((dr + 1) * 3 + 0) * 9 + ((dq + 1) * 3 + 2)]; // drx=-1,dqx=+1
                er += smS[((dr + 1) * 3 + 2) * 9 + ((dq + 1) * 3 + 0)]; // drx=+1,dqx=-1
            }
            ws[WS_ET + dd] = et;
            ws[WS_EB + dd] = eb;
            ws[WS_EL + dd] = el;
            ws[WS_ER + dd] = er;
        }
        ws[WS_C4 + 0] = smS[0 * 9 + 8];  // TL: dr=(-1,-1), dq=(1,1)
        ws[WS_C4 + 1] = smS[2 * 9 + 6];  // TR
        ws[WS_C4 + 2] = smS[6 * 9 + 2];  // BL
        ws[WS_C4 + 3] = smS[8 * 9 + 0];  // BR
    }
}

// -------------------------------------------------------------------------
// One batch of MB power-iteration steps. 256 blocks = 16x16 tiles of 16^2.
// Thread layout: q = tid&15 (4-wide column quad, buffer cols 4q..4q+3),
// strip = tid>>4 (4 output rows, buffer rows 2+4*strip .. +3); strips>=14
// idle. Per step each thread loads an 8x8 register window (b128+2*b64 per
// row), computes 16 outputs with the fused K5 (400 unrolled FMAs), applies
// image-edge corrections + zero-outside mask, writes back 4 b128s.
// -------------------------------------------------------------------------
__global__ __launch_bounds__(256) void pi_batch_kernel(
    const float* __restrict__ ws, float* __restrict__ gbuf,
    float* __restrict__ part, int batch) {
    __shared__ float bufA[BUFSZ];
    __shared__ float bufB[BUFSZ];
    __shared__ float sred[4];
    const int tid = threadIdx.x;
    const int bid = blockIdx.x;
    const int wid = tid >> 6;
    const int lane = tid & 63;
    const int q = tid & 15;
    const int strip = tid >> 4;
    const int tx = bid & 15;
    const int ty = bid >> 4;
    const float* gin = gbuf + ((batch & 1) ? HW : 0);
    float* gout      = gbuf + ((batch & 1) ? 0 : HW);

    float k5[25];
#pragma unroll
    for (int i = 0; i < 25; ++i) k5[i] = ws[WS_K5 + i];
    float et[5], eb[5], el[5], er[5], c4[4];
#pragma unroll
    for (int i = 0; i < 5; ++i) {
        et[i] = ws[WS_ET + i]; eb[i] = ws[WS_EB + i];
        el[i] = ws[WS_EL + i]; er[i] = ws[WS_ER + i];
    }
#pragma unroll
    for (int i = 0; i < 4; ++i) c4[i] = ws[WS_C4 + i];

    float inv_n;
    if (batch == 0) {
        inv_n = 1.0f / 256.0f;
    } else {
        const float* pp = part + (size_t)(batch * MB - 1) * 1024;
        float s = pp[tid] + pp[tid + 256] + pp[tid + 512] + pp[tid + 768];
#pragma unroll
        for (int o = 32; o > 0; o >>= 1) s += __shfl_down(s, o, 64);
        if (lane == 0) sred[wid] = s;
        __syncthreads();
        inv_n = 1.0f / sqrtf(sred[0] + sred[1] + sred[2] + sred[3]);
        __syncthreads();
    }

    // load region into bufA (zeros outside image / in pads); zero bufB fully
    for (int i = tid; i < BUFSZ; i += 256) {
        float v = 0.f;
        if (i >= 4) {
            int cell = i - 4;
            int r = cell >> 6, c = cell & 63;
            if (r < 60) {
                int gy = ty * 16 - 22 + r;    // region row r-2 + oy
                int gx = tx * 16 - 24 + c;    // region col c-4 + ox
                if ((unsigned)gy < IMH && (unsigned)gx < IMW)
                    v = (batch == 0) ? inv_n : gin[gy * IMW + gx] * inv_n;
            }
        }
        bufA[i] = v;
        bufB[i] = 0.f;
    }
    __syncthreads();

    // per-thread invariants
    const bool active = (strip < 14);
    const int r0 = 2 + 4 * strip;          // output rows r0..r0+3
    const int gy0 = ty * 16 - 22 + r0;
    const int gx0 = tx * 16 - 24 + 4 * q;
    bool iny[4], bt[4], bb[4];
#pragma unroll
    for (int k = 0; k < 4; ++k) {
        int gy = gy0 + k;
        iny[k] = ((unsigned)gy < IMH);
        bt[k] = (gy == 0);
        bb[k] = (gy == IMH - 1);
    }
    bool inx[4];
#pragma unroll
    for (int i = 0; i < 4; ++i) inx[i] = ((unsigned)(gx0 + i) < IMW);
    const bool bL = (gx0 == 0);
    const bool bR = (gx0 + 3 == IMW - 1);
    const bool central = (q >= 6 && q < 10) && (strip >= 5 && strip < 9);

    float* cur = bufA;
    float* nxt = bufB;
#pragma unroll 1
    for (int s = 0; s < MB; ++s) {
        float pv = 0.f;
        if (active) {
            // 8x8 register window: rows r0-2 .. r0+5, cols 4q-2 .. 4q+5
            float win[8][8];
            const int base = 4 + (r0 - 2) * BROW + 4 * q;
#pragma unroll
            for (int m = 0; m < 8; ++m) {
                float4 a = *(const float4*)&cur[base + m * BROW];
                float2 lo = *(const float2*)&cur[base + m * BROW - 2];
                float2 hi = *(const float2*)&cur[base + m * BROW + 4];
                win[m][0] = lo.x; win[m][1] = lo.y;
                win[m][2] = a.x;  win[m][3] = a.y;
                win[m][4] = a.z;  win[m][5] = a.w;
                win[m][6] = hi.x; win[m][7] = hi.y;
            }
            float z[4][4];
#pragma unroll
            for (int k = 0; k < 4; ++k) {
#pragma unroll
                for (int i = 0; i < 4; ++i) z[k][i] = 0.f;
#pragma unroll
                for (int j = 0; j < 5; ++j) {
#pragma unroll
                    for (int dx = 0; dx < 5; ++dx) {
                        const float kv = k5[j * 5 + dx];
                        z[k][0] += kv * win[k + j][0 + dx];
                        z[k][1] += kv * win[k + j][1 + dx];
                        z[k][2] += kv * win[k + j][2 + dx];
                        z[k][3] += kv * win[k + j][3 + dx];
                    }
                }
            }
            // image-edge corrections (outermost ring only)
#pragma unroll
            for (int k = 0; k < 4; ++k) {
                if (bt[k]) {
#pragma unroll
                    for (int i = 0; i < 4; ++i) {
                        float c = 0.f;
#pragma unroll
                        for (int d = 0; d < 5; ++d) c += et[d] * win[k + 2][i + d];
                        z[k][i] -= c;
                    }
                }
                if (bb[k]) {
#pragma unroll
                    for (int i = 0; i < 4; ++i) {
                        float c = 0.f;
#pragma unroll
                        for (int d = 0; d < 5; ++d) c += eb[d] * win[k + 2][i + d];
                        z[k][i] -= c;
                    }
                }
            }
            if (bL) {
#pragma unroll
                for (int k = 0; k < 4; ++k) {
                    float c = 0.f;
#pragma unroll
                    for (int j = 0; j < 5; ++j) c += el[j] * win[k + j][2];
                    z[k][0] -= c;
                    if (bt[k]) z[k][0] += c4[0] * win[k + 2][2];
                    if (bb[k]) z[k][0] += c4[2] * win[k + 2][2];
                }
            }
            if (bR) {
#pragma unroll
                for (int k = 0; k < 4; ++k) {
                    float c = 0.f;
#pragma unroll
                    for (int j = 0; j < 5; ++j) c += er[j] * win[k + j][5];
                    z[k][3] -= c;
                    if (bt[k]) z[k][3] += c4[1] * win[k + 2][5];
                    if (bb[k]) z[k][3] += c4[3] * win[k + 2][5];
                }
            }
            // zero-outside mask, store, central-norm partial
#pragma unroll
            for (int k = 0; k < 4; ++k) {
                float4 o;
                o.x = (iny[k] && inx[0]) ? z[k][0] : 0.f;
                o.y = (iny[k] && inx[1]) ? z[k][1] : 0.f;
                o.z = (iny[k] && inx[2]) ? z[k][2] : 0.f;
                o.w = (iny[k] && inx[3]) ? z[k][3] : 0.f;
                *(float4*)&nxt[4 + (r0 + k) * BROW + 4 * q] = o;
                if (central)
                    pv += o.x * o.x + o.y * o.y + o.z * o.z + o.w * o.w;
            }
        }
        // per-wave reduce; wave leader stores to its private slot
#pragma unroll
        for (int o = 32; o > 0; o >>= 1) pv += __shfl_down(pv, o, 64);
        if (lane == 0)
            part[(size_t)(batch * MB + s) * 1024 + (bid << 2) + wid] = pv;
        __syncthreads();
        float* tmp = cur; cur = nxt; nxt = tmp;
    }

    // write central 16x16 tile (64 threads x float4)
    if (tid < 64) {
        int rr = tid >> 2, cq = tid & 3;
        float4 v = *(const float4*)&cur[4 + (22 + rr) * BROW + 24 + 4 * cq];
        int gy = ty * 16 + rr, gx = tx * 16 + 4 * cq;
        *(float4*)&gout[gy * IMW + gx] = v;
    }
}

// -------------------------------------------------------------------------
// Sum the 1024 per-wave partials of each level into ws norm slots.
// -------------------------------------------------------------------------
__global__ __launch_bounds__(256) void reduce_kernel(
    const float* __restrict__ part, float* __restrict__ ws) {
    const int lev = blockIdx.x;       // 0..299
    const int t = threadIdx.x;
    __shared__ float sr[4];
    const float* pp = part + (size_t)lev * 1024;
    float s = pp[t] + pp[t + 256] + pp[t + 512] + pp[t + 768];
#pragma unroll
    for (int o = 32; o > 0; o >>= 1) s += __shfl_down(s, o, 64);
    if ((t & 63) == 0) sr[t >> 6] = s;
    __syncthreads();
    if (t == 0) ws[WS_ACC + 1 + lev] = sr[0] + sr[1] + sr[2] + sr[3];
}

// -------------------------------------------------------------------------
// Replay the exact while-loop stopping rule on the recorded norm sequence.
// -------------------------------------------------------------------------
__global__ void finalize_kernel(float* __restrict__ ws,
                                const float* __restrict__ beta,
                                const float* __restrict__ log_sigma) {
    if (threadIdx.x != 0 || blockIdx.x != 0) return;
    float val = 1.0f;
    int k = 0;
    bool stopped = false;
    for (int b = 0; b < NBATCH && !stopped; ++b) {
        float nprev = 1.0f;
        for (int s = 1; s <= MB; ++s) {
            float n = sqrtf(ws[WS_ACC + b * MB + s]);
            float v = n / nprev;
            nprev = n;
            float rel = fabsf(v - val) / val;
            val = v;
            ++k;
            if (rel < 1e-4f || k >= 300) { stopped = true; break; }
        }
    }
    float lip2 = val;
    float sigma = expf(log_sigma[0]) + 0.05f;
    float tau = 0.99f / (beta[0] * 0.5f + sigma * lip2);
    ws[WS_LIP2] = lip2;
    ws[WS_TAU] = tau;
    ws[WS_SIGMA] = sigma;
}

// -------------------------------------------------------------------------
// output0: Dx = x - tau*(HtH.*x) - tau*conv_t(u) + tau*bias; clip [0,1]
// wave = one image row; lane = 4-px quad (float4); x-halo via shuffles.
// -------------------------------------------------------------------------
__global__ __launch_bounds__(256) void out0_kernel(
    const float* __restrict__ x_in, const float* __restrict__ u_in,
    const float* __restrict__ bias, const float* __restrict__ HtH,
    const float* __restrict__ w, const float* __restrict__ ws,
    float* __restrict__ out0) {
    const int tid = threadIdx.x;
    const int lane = tid & 63;
    const int wid = tid >> 6;
    const int y = blockIdx.x * 4 + wid;
    const int b = blockIdx.y;
    const int x0 = lane * 4;
    const float tau = ws[WS_TAU];
    float4 ct = {0.f, 0.f, 0.f, 0.f};
    const float* ub = u_in + (size_t)b * NF * HW;
#pragma unroll 4
    for (int f = 0; f < NF; ++f) {
        const float* uf = ub + (size_t)f * HW;
        const float* wf = w + f * 9;
#pragma unroll
        for (int dy = -1; dy <= 1; ++dy) {
            int yy = y + dy;
            float4 v = {0.f, 0.f, 0.f, 0.f};
            if ((unsigned)yy < IMH)
                v = *(const float4*)(uf + yy * IMW + x0);
            float m1 = __shfl_up(v.w, 1);
            if (lane == 0) m1 = 0.f;
            float p4 = __shfl_down(v.x, 1);
            if (lane == 63) p4 = 0.f;
            const float w2 = wf[(1 - dy) * 3 + 2];   // dx=-1
            const float w1 = wf[(1 - dy) * 3 + 1];   // dx= 0
            const float w0 = wf[(1 - dy) * 3 + 0];   // dx=+1
            ct.x += w2 * m1  + w1 * v.x + w0 * v.y;
            ct.y += w2 * v.x + w1 * v.y + w0 * v.z;
            ct.z += w2 * v.y + w1 * v.z + w0 * v.w;
            ct.w += w2 * v.z + w1 * v.w + w0 * p4;
        }
    }
    const int p = y * IMW + x0;
    const float4 xi = *(const float4*)(x_in + (size_t)b * HW + p);
    const float4 hh = *(const float4*)(HtH + p);
    const float4 bs = *(const float4*)(bias + (size_t)b * HW + p);
    float4 o;
    o.x = fminf(fmaxf(xi.x - tau * (hh.x * xi.x) - tau * ct.x + tau * bs.x, 0.f), 1.f);
    o.y = fminf(fmaxf(xi.y - tau * (hh.y * xi.y) - tau * ct.y + tau * bs.y, 0.f), 1.f);
    o.z = fminf(fmaxf(xi.z - tau * (hh.z * xi.z) - tau * ct.z + tau * bs.z, 0.f), 1.f);
    o.w = fminf(fmaxf(xi.w - tau * (hh.w * xi.w) - tau * ct.w + tau * bs.w, 0.f), 1.f);
    *(float4*)(out0 + (size_t)b * HW + p) = o;
}

// -------------------------------------------------------------------------
// output1: Du = 2*sigma*conv(out0)_f - sigma*conv(x_in)_f + u; clip [-lam,lam]
// -------------------------------------------------------------------------
__global__ __launch_bounds__(256) void out1_kernel(
    const float* __restrict__ x_in, const float* __restrict__ u_in,
    const float* __restrict__ lambd, const float* __restrict__ w,
    const float* __restrict__ ws, const float* __restrict__ out0,
    float* __restrict__ out1) {
    const int tid = threadIdx.x;
    const int lane = tid & 63;
    const int wid = tid >> 6;
    const int y = blockIdx.x * 4 + wid;
    const int f = blockIdx.y;
    const int b = blockIdx.z;
    const int x0 = lane * 4;
    const float sigma = ws[WS_SIGMA];
    const float lam = lambd[0];
    const float* wf = w + f * 9;
    float wr[9];
#pragma unroll
    for (int i = 0; i < 9; ++i) wr[i] = wf[i];
    const float* o0 = out0 + (size_t)b * HW;
    const float* xb = x_in + (size_t)b * HW;
    float4 s1 = {0.f, 0.f, 0.f, 0.f};
    float4 s2 = {0.f, 0.f, 0.f, 0.f};
#pragma unroll
    for (int dy = -1; dy <= 1; ++dy) {
        int yy = y + dy;
        float4 a = {0.f, 0.f, 0.f, 0.f};
        float4 c = {0.f, 0.f, 0.f, 0.f};
        if ((unsigned)yy < IMH) {
            a = *(const float4*)(o0 + yy * IMW + x0);
            c = *(const float4*)(xb + yy * IMW + x0);
        }
        float am1 = __shfl_up(a.w, 1);  if (lane == 0) am1 = 0.f;
        float ap4 = __shfl_down(a.x, 1); if (lane == 63) ap4 = 0.f;
        float cm1 = __shfl_up(c.w, 1);  if (lane == 0) cm1 = 0.f;
        float cp4 = __shfl_down(c.x, 1); if (lane == 63) cp4 = 0.f;
        const float w0 = wr[(dy + 1) * 3 + 0];
        const float w1 = wr[(dy + 1) * 3 + 1];
        const float w2 = wr[(dy + 1) * 3 + 2];
        s1.x += w0 * am1 + w1 * a.x + w2 * a.y;
        s1.y += w0 * a.x + w1 * a.y + w2 * a.z;
        s1.z += w0 * a.y + w1 * a.z + w2 * a.w;
        s1.w += w0 * a.z + w1 * a.w + w2 * ap4;
        s2.x += w0 * cm1 + w1 * c.x + w2 * c.y;
        s2.y += w0 * c.x + w1 * c.y + w2 * c.z;
        s2.z += w0 * c.y + w1 * c.z + w2 * c.w;
        s2.w += w0 * c.z + w1 * c.w + w2 * cp4;
    }
    const size_t idx = (size_t)(b * NF + f) * HW + y * IMW + x0;
    const float4 uq = *(const float4*)(u_in + idx);
    float4 o;
    o.x = fminf(fmaxf(2.f * sigma * s1.x - sigma * s2.x + uq.x, -lam), lam);
    o.y = fminf(fmaxf(2.f * sigma * s1.y - sigma * s2.y + uq.y, -lam), lam);
    o.z = fminf(fmaxf(2.f * sigma * s1.z - sigma * s2.z + uq.z, -lam), lam);
    o.w = fminf(fmaxf(2.f * sigma * s1.w - sigma * s2.w + uq.w, -lam), lam);
    *(float4*)(out1 + idx) = o;
}

extern "C" void kernel_launch(void* const* d_in, const int* in_sizes, int n_in,
                              void* d_out, int out_size, void* d_ws, size_t ws_size,
                              hipStream_t stream) {
    const float* x_in = (const float*)d_in[0];
    const float* u_in = (const float*)d_in[1];
    const float* bias = (const float*)d_in[2];
    const float* beta = (const float*)d_in[3];
    const float* lambd = (const float*)d_in[4];
    const float* HtH = (const float*)d_in[5];
    const float* w = (const float*)d_in[6];
    const float* log_sigma = (const float*)d_in[7];
    float* ws = (float*)d_ws;
    float* out0 = (float*)d_out;
    float* out1 = out0 + (size_t)NBT * HW;
    // scratch lives in the (not yet written) output1 region:
    //   gbuf: 2*HW floats ping-pong image; part: 300*1024 per-wave partials
    float* gbuf = out1;
    float* part = out1 + 2 * HW;

    setup_kernel<<<1, 128, 0, stream>>>(w, ws);
    for (int b = 0; b < NBATCH; ++b)
        pi_batch_kernel<<<256, 256, 0, stream>>>(ws, gbuf, part, b);
    reduce_kernel<<<300, 256, 0, stream>>>(part, ws);
    finalize_kernel<<<1, 64, 0, stream>>>(ws, beta, log_sigma);
    out0_kernel<<<dim3(IMH / 4, NBT), 256, 0, stream>>>(x_in, u_in, bias, HtH, w, ws, out0);
    out1_kernel<<<dim3(IMH / 4, NF, NBT), 256, 0, stream>>>(x_in, u_in, lambd, w, ws, out0, out1);
}